// Round 10
// baseline (384.353 us; speedup 1.0000x reference)
//
#include <hip/hip_runtime.h>

// GIN layer: agg = segment_sum(x[col], row); h = (1+eps)*x + agg;
// h = h@W1.T + b1; BN(train); ReLU; out = h@W2.T + b2
// N=100000, E=1600000, F=128. Inputs fp32; internal bf16 + MFMA.

#define F 128
#define CHK 1024        // scan chunk size

typedef __attribute__((ext_vector_type(8))) short short8;
typedef __attribute__((ext_vector_type(4))) float float4v;

__device__ inline float b2f(unsigned short u) {
    union { unsigned int i; float f; } v; v.i = ((unsigned int)u) << 16; return v.f;
}
__device__ inline unsigned short f2b(float f) {
    union { float f; unsigned int i; } v; v.f = f;
    unsigned int r = v.i + 0x7FFFu + ((v.i >> 16) & 1u);
    return (unsigned short)(r >> 16);
}

// ---------- K0: convert x -> bf16, W1,W2 -> bf16, zero cnt/used/stats (fused) ----------
__global__ __launch_bounds__(256) void conv_kernel(const float* __restrict__ x,
                                                   unsigned short* __restrict__ xh, int total,
                                                   const float* __restrict__ W1,
                                                   const float* __restrict__ W2,
                                                   unsigned short* __restrict__ w1h,
                                                   unsigned short* __restrict__ w2h,
                                                   int* __restrict__ cnt, int* __restrict__ used,
                                                   int n, float* __restrict__ stats) {
    int t = blockIdx.x * 256 + threadIdx.x;
    int i = t * 8;
    if (i < total) {
        float4 v0 = *(const float4*)(x + i);
        float4 v1 = *(const float4*)(x + i + 4);
        short8 o;
        o[0] = (short)f2b(v0.x); o[1] = (short)f2b(v0.y); o[2] = (short)f2b(v0.z); o[3] = (short)f2b(v0.w);
        o[4] = (short)f2b(v1.x); o[5] = (short)f2b(v1.y); o[6] = (short)f2b(v1.z); o[7] = (short)f2b(v1.w);
        *(short8*)(xh + i) = o;
    }
    if (t < F * F) {
        w1h[t] = f2b(W1[t]);
        w2h[t] = f2b(W2[t]);
    }
    if (t < n) { cnt[t] = 0; used[t] = 0; }
    if (t < 256 && blockIdx.x == 0) { /* covered below by t<n? no: stats separate */ }
    if (blockIdx.x == 1 && threadIdx.x < 256) stats[threadIdx.x] = 0.f;
}

// ---------- K1: per-node degree histogram (atomics over 100K addresses, depth ~16) ----------
__global__ __launch_bounds__(256) void edge_hist_kernel(const int* __restrict__ rows,
                                                        int* __restrict__ cnt, int E) {
    int stride = gridDim.x * 256;
    for (int i = blockIdx.x * 256 + threadIdx.x; i < E; i += stride)
        atomicAdd(&cnt[rows[i]], 1);
}

// ---------- K2a: per-chunk exclusive scan of cnt -> eoff, chunk totals -> btot ----------
__global__ __launch_bounds__(1024) void scan_chunk_kernel(const int* __restrict__ cnt,
                                                          int* __restrict__ eoff,
                                                          int* __restrict__ btot, int n) {
    __shared__ int wsum[16];
    int t = threadIdx.x;
    int i = blockIdx.x * CHK + t;
    int v = (i < n) ? cnt[i] : 0;
    int lane = t & 63, wv = t >> 6;
    int x = v;
#pragma unroll
    for (int off = 1; off < 64; off <<= 1) {
        int u = __shfl_up(x, off, 64);
        if (lane >= off) x += u;
    }
    if (lane == 63) wsum[wv] = x;
    __syncthreads();
    if (wv == 0 && lane < 16) {
        int w = wsum[lane];
        int y = w;
#pragma unroll
        for (int off = 1; off < 16; off <<= 1) {
            int u = __shfl_up(y, off, 64);
            if (lane >= off) y += u;
        }
        wsum[lane] = y - w;   // exclusive wave base
    }
    __syncthreads();
    int excl = (x - v) + wsum[wv];
    if (i <= n) eoff[i] = excl;
    if (t == CHK - 1) btot[blockIdx.x] = excl + v;
}

// ---------- K2b: exclusive scan of chunk totals -> cbase ----------
__global__ void scan_base_kernel(const int* __restrict__ btot, int* __restrict__ cbase,
                                 int nchunk) {
    __shared__ int tmp[128];
    int t = threadIdx.x;
    int v = (t < nchunk) ? btot[t] : 0;
    tmp[t] = v;
    __syncthreads();
    for (int off = 1; off < 128; off <<= 1) {
        int u = (t >= off) ? tmp[t - off] : 0;
        __syncthreads();
        tmp[t] += u;
        __syncthreads();
    }
    if (t < nchunk) cbase[t] = tmp[t] - v;
}

// ---------- K3: direct scatter: clist[offs[r] + rank] = c ----------
__global__ __launch_bounds__(256) void scatter_kernel(const int* __restrict__ rows,
                                                      const int* __restrict__ cols,
                                                      const int* __restrict__ eoff,
                                                      const int* __restrict__ cbase,
                                                      int* __restrict__ used,
                                                      int* __restrict__ clist, int E) {
    int stride = gridDim.x * 256;
    for (int i = blockIdx.x * 256 + threadIdx.x; i < E; i += stride) {
        int r = rows[i], c = cols[i];
        int rank = atomicAdd(&used[r], 1);
        clist[eoff[r] + cbase[r >> 10] + rank] = c;
    }
}

// ---------- K4: gather-aggregate in bf16: h0h = bf16((1+eps)*x + sum_nb x) ----------
// One wave per node. 16 lanes per row (short8 = 16B/lane), 4-way edge interleave.
__global__ __launch_bounds__(256) void agg_kernel(const unsigned short* __restrict__ xh,
                                                  const int* __restrict__ eoff,
                                                  const int* __restrict__ cbase,
                                                  const int* __restrict__ clist,
                                                  const float* __restrict__ epsPtr,
                                                  unsigned short* __restrict__ h0h, int n) {
    int wave = threadIdx.x >> 6, lane = threadIdx.x & 63;
    int node = blockIdx.x * 4 + wave;
    if (node >= n) return;
    int qt = lane >> 4;          // which edge within group of 4
    int c16 = lane & 15;         // channel chunk: channels 8*c16 .. 8*c16+7
    const short8* xh8 = (const short8*)xh;   // row r chunk c -> index r*16 + c
    float acc[8];
#pragma unroll
    for (int j = 0; j < 8; j++) acc[j] = 0.f;
    int s = eoff[node] + cbase[node >> 10];
    int e = eoff[node + 1] + cbase[(node + 1) >> 10];
    int i = s;
    for (; i + 16 <= e; i += 16) {
        int c[4];
#pragma unroll
        for (int u = 0; u < 4; u++) c[u] = clist[i + 4 * u + qt];
        short8 v[4];
#pragma unroll
        for (int u = 0; u < 4; u++) v[u] = xh8[(size_t)c[u] * 16 + c16];
#pragma unroll
        for (int u = 0; u < 4; u++)
#pragma unroll
            for (int j = 0; j < 8; j++) acc[j] += b2f((unsigned short)v[u][j]);
    }
    if (i < e) {
        int c[4];
#pragma unroll
        for (int u = 0; u < 4; u++) {
            int idx = i + 4 * u + qt;
            c[u] = (idx < e) ? clist[idx] : -1;
        }
        short8 v[4];
#pragma unroll
        for (int u = 0; u < 4; u++)
            v[u] = xh8[(size_t)(c[u] < 0 ? 0 : c[u]) * 16 + c16];
#pragma unroll
        for (int u = 0; u < 4; u++) {
            if (c[u] >= 0) {
#pragma unroll
                for (int j = 0; j < 8; j++) acc[j] += b2f((unsigned short)v[u][j]);
            }
        }
    }
#pragma unroll
    for (int j = 0; j < 8; j++) {
        acc[j] += __shfl_xor(acc[j], 16, 64);
        acc[j] += __shfl_xor(acc[j], 32, 64);
    }
    if (qt == 0) {
        float sc = 1.0f + epsPtr[0];
        short8 xv = xh8[(size_t)node * 16 + c16];
        short8 o;
#pragma unroll
        for (int j = 0; j < 8; j++) {
            float r = fmaf(sc, b2f((unsigned short)xv[j]), acc[j]);
            o[j] = (short)f2b(r);
        }
        ((short8*)h0h)[(size_t)node * 16 + c16] = o;
    }
}

// ---------- K5: MFMA GEMM1: h1 = h0h @ W1^T + b1 (bf16 in, fp32 acc) + BN partials ----------
// Stats epilogue is ATOMIC-FREE: per-block partial sums -> partials[block][256].
#define WLD 136   // padded LDS row stride (elements)
__global__ __launch_bounds__(256, 2) void gemm1_mfma_kernel(const unsigned short* __restrict__ h0h,
                                                            const unsigned short* __restrict__ w1h,
                                                            const float* __restrict__ b1,
                                                            unsigned short* __restrict__ h1h,
                                                            float* __restrict__ partials, int n) {
    __shared__ unsigned short wl[128 * WLD];
    __shared__ float red[4 * 256];
    int tid = threadIdx.x;
    for (int i = tid; i < 128 * 16; i += 256) {
        int r = i >> 4, ch = i & 15;
        *(short8*)(wl + r * WLD + ch * 8) = *(const short8*)(w1h + r * 128 + ch * 8);
    }
    __syncthreads();

    int wv = tid >> 6, lane = tid & 63;
    int q = lane >> 4, c15 = lane & 15;
    int rowbase = blockIdx.x * 64 + wv * 16;
    int arow = rowbase + c15; if (arow >= n) arow = n - 1;
    const unsigned short* aptr = h0h + (size_t)arow * 128 + q * 8;

    float4v acc[8];
#pragma unroll
    for (int nt = 0; nt < 8; nt++) {
        float bb = b1[nt * 16 + c15];
        acc[nt] = (float4v){bb, bb, bb, bb};
    }
#pragma unroll
    for (int ks = 0; ks < 4; ks++) {
        short8 a = *(const short8*)(aptr + ks * 32);
        const unsigned short* wp = wl + q * 8 + ks * 32;
#pragma unroll
        for (int nt = 0; nt < 8; nt++) {
            short8 b = *(const short8*)(wp + (nt * 16 + c15) * WLD);
            acc[nt] = __builtin_amdgcn_mfma_f32_16x16x32_bf16(a, b, acc[nt], 0, 0, 0);
        }
    }

    // epilogue: store h1h (bf16) + per-col partial sums (no global atomics)
    float sum[8], sq[8];
#pragma unroll
    for (int nt = 0; nt < 8; nt++) {
        sum[nt] = 0.f; sq[nt] = 0.f;
#pragma unroll
        for (int r = 0; r < 4; r++) {
            int row = rowbase + q * 4 + r;
            if (row < n) {
                float v = acc[nt][r];
                h1h[(size_t)row * 128 + nt * 16 + c15] = f2b(v);
                sum[nt] += v; sq[nt] += v * v;
            }
        }
        sum[nt] += __shfl_xor(sum[nt], 16, 64);
        sum[nt] += __shfl_xor(sum[nt], 32, 64);
        sq[nt]  += __shfl_xor(sq[nt], 16, 64);
        sq[nt]  += __shfl_xor(sq[nt], 32, 64);
    }
    if (lane < 16) {
#pragma unroll
        for (int nt = 0; nt < 8; nt++) {
            red[wv * 256 + nt * 16 + c15] = sum[nt];
            red[wv * 256 + 128 + nt * 16 + c15] = sq[nt];
        }
    }
    __syncthreads();
    if (wv == 0) {
        float* pout = partials + (size_t)blockIdx.x * 256;
        for (int c = lane; c < 128; c += 64) {
            float S = red[c] + red[256 + c] + red[512 + c] + red[768 + c];
            float Q = red[128 + c] + red[384 + c] + red[640 + c] + red[896 + c];
            pout[c] = S;
            pout[128 + c] = Q;
        }
    }
}

// ---------- K6: reduce per-block partials -> stats (16-deep atomic chains only) ----------
__global__ __launch_bounds__(256) void bn_reduce_kernel(const float* __restrict__ partials,
                                                        float* __restrict__ stats, int nb) {
    int t = threadIdx.x;
    int per = (nb + gridDim.x - 1) / gridDim.x;
    int j0 = blockIdx.x * per, j1 = min(nb, j0 + per);
    float s = 0.f;
    for (int j = j0; j < j1; j++) s += partials[(size_t)j * 256 + t];
    atomicAdd(&stats[t], s);
}

// ---------- K7: MFMA GEMM2: out = relu(BN(h1h)) @ W2^T + b2, fp32 out ----------
// BN finalize fused into prologue: each block derives scale/shift from stats.
__global__ __launch_bounds__(256, 2) void gemm2_mfma_kernel(const unsigned short* __restrict__ h1h,
                                                            const unsigned short* __restrict__ w2h,
                                                            const float* __restrict__ b2,
                                                            const float* __restrict__ stats,
                                                            const float* __restrict__ gamma,
                                                            const float* __restrict__ beta,
                                                            float* __restrict__ out, int n) {
    __shared__ unsigned short wl[128 * WLD];
    __shared__ float ssl[256];
    int tid = threadIdx.x;
    for (int i = tid; i < 128 * 16; i += 256) {
        int r = i >> 4, ch = i & 15;
        *(short8*)(wl + r * WLD + ch * 8) = *(const short8*)(w2h + r * 128 + ch * 8);
    }
    if (tid < 128) {
        float inv_n = 1.0f / (float)n;
        float mu = stats[tid] * inv_n;
        float var = stats[F + tid] * inv_n - mu * mu;
        var = fmaxf(var, 0.0f);
        float rs = rsqrtf(var + 1e-5f);
        float s = gamma[tid] * rs;
        ssl[tid] = s;
        ssl[F + tid] = beta[tid] - mu * s;
    }
    __syncthreads();

    int wv = tid >> 6, lane = tid & 63;
    int q = lane >> 4, c15 = lane & 15;
    int rowbase = blockIdx.x * 64 + wv * 16;
    int arow = rowbase + c15; if (arow >= n) arow = n - 1;
    const unsigned short* aptr = h1h + (size_t)arow * 128 + q * 8;

    float4v acc[8];
#pragma unroll
    for (int nt = 0; nt < 8; nt++) {
        float bb = b2[nt * 16 + c15];
        acc[nt] = (float4v){bb, bb, bb, bb};
    }
#pragma unroll
    for (int ks = 0; ks < 4; ks++) {
        short8 araw = *(const short8*)(aptr + ks * 32);
        const float* ssp = ssl + ks * 32 + q * 8;
        float4 s0 = *(const float4*)(ssp);
        float4 s1 = *(const float4*)(ssp + 4);
        float4 t0 = *(const float4*)(ssp + 128);
        float4 t1 = *(const float4*)(ssp + 132);
        short8 a;
        a[0] = (short)f2b(fmaxf(fmaf(b2f((unsigned short)araw[0]), s0.x, t0.x), 0.f));
        a[1] = (short)f2b(fmaxf(fmaf(b2f((unsigned short)araw[1]), s0.y, t0.y), 0.f));
        a[2] = (short)f2b(fmaxf(fmaf(b2f((unsigned short)araw[2]), s0.z, t0.z), 0.f));
        a[3] = (short)f2b(fmaxf(fmaf(b2f((unsigned short)araw[3]), s0.w, t0.w), 0.f));
        a[4] = (short)f2b(fmaxf(fmaf(b2f((unsigned short)araw[4]), s1.x, t1.x), 0.f));
        a[5] = (short)f2b(fmaxf(fmaf(b2f((unsigned short)araw[5]), s1.y, t1.y), 0.f));
        a[6] = (short)f2b(fmaxf(fmaf(b2f((unsigned short)araw[6]), s1.z, t1.z), 0.f));
        a[7] = (short)f2b(fmaxf(fmaf(b2f((unsigned short)araw[7]), s1.w, t1.w), 0.f));
        const unsigned short* wp = wl + q * 8 + ks * 32;
#pragma unroll
        for (int nt = 0; nt < 8; nt++) {
            short8 b = *(const short8*)(wp + (nt * 16 + c15) * WLD);
            acc[nt] = __builtin_amdgcn_mfma_f32_16x16x32_bf16(a, b, acc[nt], 0, 0, 0);
        }
    }
#pragma unroll
    for (int nt = 0; nt < 8; nt++) {
#pragma unroll
        for (int r = 0; r < 4; r++) {
            int row = rowbase + q * 4 + r;
            if (row < n)
                out[(size_t)row * 128 + nt * 16 + c15] = acc[nt][r];
        }
    }
}

extern "C" void kernel_launch(void* const* d_in, const int* in_sizes, int n_in,
                              void* d_out, int out_size, void* d_ws, size_t ws_size,
                              hipStream_t stream) {
    const float* x     = (const float*)d_in[0];
    const int*   ei    = (const int*)d_in[1];
    const float* eps   = (const float*)d_in[2];
    const float* W1    = (const float*)d_in[3];
    const float* b1    = (const float*)d_in[4];
    const float* gamma = (const float*)d_in[5];
    const float* beta  = (const float*)d_in[6];
    const float* W2    = (const float*)d_in[7];
    const float* b2    = (const float*)d_in[8];
    float* out = (float*)d_out;

    const int E = in_sizes[1] / 2;
    const int n = in_sizes[0] / F;
    const int nchunk = n / CHK + 1;         // covers index n inclusive
    const int ntiles = (n + 63) / 64;       // 1563

    char* w = (char*)d_ws;
    auto alloc = [&](size_t bytes) -> void* {
        void* p = (void*)w;
        w += (bytes + 255) & ~(size_t)255;
        return p;
    };
    int*            cnt      = (int*)alloc((size_t)n * 4);
    int*            used     = (int*)alloc((size_t)n * 4);
    int*            eoff     = (int*)alloc((size_t)(n + 2) * 4);
    int*            btot     = (int*)alloc((size_t)nchunk * 4);
    int*            cbase    = (int*)alloc((size_t)nchunk * 4);
    float*          stats    = (float*)alloc(256 * 4);
    float*          partials = (float*)alloc((size_t)ntiles * 256 * 4);
    unsigned short* w1h      = (unsigned short*)alloc(F * F * 2);
    unsigned short* w2h      = (unsigned short*)alloc(F * F * 2);
    int*            clist    = (int*)alloc((size_t)E * 4);
    unsigned short* xh       = (unsigned short*)alloc((size_t)n * F * 2);
    unsigned short* h0h      = (unsigned short*)alloc((size_t)n * F * 2);
    unsigned short* h1h      = (unsigned short*)alloc((size_t)n * F * 2);

    const int* rows = ei;
    const int* cols = ei + E;

    conv_kernel<<<(n * F / 8 + 255) / 256, 256, 0, stream>>>(x, xh, n * F, W1, W2, w1h, w2h,
                                                             cnt, used, n, stats);
    edge_hist_kernel<<<1024, 256, 0, stream>>>(rows, cnt, E);
    scan_chunk_kernel<<<nchunk, CHK, 0, stream>>>(cnt, eoff, btot, n);
    scan_base_kernel<<<1, 128, 0, stream>>>(btot, cbase, nchunk);
    scatter_kernel<<<1024, 256, 0, stream>>>(rows, cols, eoff, cbase, used, clist, E);
    agg_kernel<<<(n + 3) / 4, 256, 0, stream>>>(xh, eoff, cbase, clist, eps, h0h, n);

    gemm1_mfma_kernel<<<ntiles, 256, 0, stream>>>(h0h, w1h, b1, h1h, partials, n);
    bn_reduce_kernel<<<16, 256, 0, stream>>>(partials, stats, ntiles);
    gemm2_mfma_kernel<<<ntiles, 256, 0, stream>>>(h1h, w2h, b2, stats, gamma, beta, out, n);
}

// Round 11
// 293.413 us; speedup vs baseline: 1.3099x; 1.3099x over previous
//
#include <hip/hip_runtime.h>

// GIN layer: agg = segment_sum(x[col], row); h = (1+eps)*x + agg;
// h = h@W1.T + b1; BN(train); ReLU; out = h@W2.T + b2
// N=100000, E=1600000, F=128. Inputs fp32; internal bf16 + MFMA.

#define F 128
#define NPB 64          // nodes per bucket
#define NBUKMAX 1600    // static LDS bound for buckets
#define RECCAP 12544    // staged recs per scatter block (>= ceil(E/SB))

typedef __attribute__((ext_vector_type(8))) short short8;
typedef __attribute__((ext_vector_type(4))) float float4v;

__device__ inline float b2f(unsigned short u) {
    union { unsigned int i; float f; } v; v.i = ((unsigned int)u) << 16; return v.f;
}
__device__ inline unsigned short f2b(float f) {
    union { float f; unsigned int i; } v; v.f = f;
    unsigned int r = v.i + 0x7FFFu + ((v.i >> 16) & 1u);
    return (unsigned short)(r >> 16);
}

// ---------- K0: convert x -> bf16, W1,W2 -> bf16, zero bucketCnt+stats (fused) ----------
__global__ __launch_bounds__(256) void conv_kernel(const float* __restrict__ x,
                                                   unsigned short* __restrict__ xh, int total,
                                                   const float* __restrict__ W1,
                                                   const float* __restrict__ W2,
                                                   unsigned short* __restrict__ w1h,
                                                   unsigned short* __restrict__ w2h,
                                                   int* __restrict__ bucketCnt, int nbuk,
                                                   float* __restrict__ stats) {
    int t = blockIdx.x * 256 + threadIdx.x;
    int i = t * 8;
    if (i < total) {
        float4 v0 = *(const float4*)(x + i);
        float4 v1 = *(const float4*)(x + i + 4);
        short8 o;
        o[0] = (short)f2b(v0.x); o[1] = (short)f2b(v0.y); o[2] = (short)f2b(v0.z); o[3] = (short)f2b(v0.w);
        o[4] = (short)f2b(v1.x); o[5] = (short)f2b(v1.y); o[6] = (short)f2b(v1.z); o[7] = (short)f2b(v1.w);
        *(short8*)(xh + i) = o;
    }
    if (t < F * F) {
        w1h[t] = f2b(W1[t]);
        w2h[t] = f2b(W2[t]);
    }
    if (blockIdx.x == 0) {
        for (int k = threadIdx.x; k < nbuk; k += 256) bucketCnt[k] = 0;
    } else if (blockIdx.x == 1) {
        if (threadIdx.x < 256) stats[threadIdx.x] = 0.f;
    }
}

// ---------- K1: bucket histogram (LDS-aggregated) ----------
__global__ __launch_bounds__(256) void bucket_hist_kernel(const int* __restrict__ rows,
                                                          int* __restrict__ bucketCnt,
                                                          int E, int nbuk) {
    extern __shared__ int bh[];
    int tid = threadIdx.x;
    for (int i = tid; i < nbuk; i += 256) bh[i] = 0;
    __syncthreads();
    int stride = gridDim.x * 256;
    for (int i = blockIdx.x * 256 + tid; i < E; i += stride)
        atomicAdd(&bh[rows[i] >> 6], 1);
    __syncthreads();
    for (int b = tid; b < nbuk; b += 256) {
        int c = bh[b];
        if (c) atomicAdd(&bucketCnt[b], c);
    }
}

// ---------- K2: exclusive scan of bucket counts ----------
__global__ void scan_buckets_kernel(const int* __restrict__ bucketCnt, int* __restrict__ bOffs,
                                    int* __restrict__ gcursor, int nbuk) {
    const int SEG = 7;
    __shared__ int tmp[256];
    int t = threadIdx.x;
    int base = t * SEG;
    int v[SEG], s = 0;
#pragma unroll
    for (int j = 0; j < SEG; j++) {
        int idx = base + j;
        v[j] = (idx < nbuk) ? bucketCnt[idx] : 0;
        s += v[j];
    }
    tmp[t] = s;
    __syncthreads();
    for (int off = 1; off < 256; off <<= 1) {
        int u = (t >= off) ? tmp[t - off] : 0;
        __syncthreads();
        tmp[t] += u;
        __syncthreads();
    }
    int run = tmp[t] - s;
#pragma unroll
    for (int j = 0; j < SEG; j++) {
        int idx = base + j;
        if (idx < nbuk) { bOffs[idx] = run; gcursor[idx] = run; }
        run += v[j];
    }
    if (t == 255) bOffs[nbuk] = tmp[255];
}

// ---------- K3: LDS-staged binned scatter ----------
// Block sorts its edge chunk by bucket in LDS, reserves one contiguous global
// segment per bucket, then flushes each bucket's run with coalesced writes.
__global__ __launch_bounds__(1024) void binned_scatter_kernel(const int* __restrict__ rows,
                                                              const int* __restrict__ cols,
                                                              int* __restrict__ gcursor,
                                                              int* __restrict__ recbuf,
                                                              int E, int nbuk) {
    __shared__ int cur[NBUKMAX];        // hist -> place-cursor -> global base
    __shared__ int lb[NBUKMAX + 1];     // exclusive prefix (local)
    __shared__ int recs[RECCAP];        // staged records, bucket-sorted
    __shared__ int wsum[17];
    int tid = threadIdx.x;
    int lane = tid & 63, wv = tid >> 6;
    int chunk = (E + gridDim.x - 1) / gridDim.x;
    int e0 = blockIdx.x * chunk;
    int e1 = min(E, e0 + chunk);
    // phase 1: hist into cur
    for (int k = tid; k < nbuk; k += 1024) cur[k] = 0;
    __syncthreads();
    for (int i = e0 + tid; i < e1; i += 1024)
        atomicAdd(&cur[rows[i] >> 6], 1);
    __syncthreads();
    // phase 2: exclusive scan cur -> lb (2 entries/thread, register wave scan)
    {
        int i0 = 2 * tid, i1 = 2 * tid + 1;
        int c0 = (i0 < nbuk) ? cur[i0] : 0;
        int c1 = (i1 < nbuk) ? cur[i1] : 0;
        int s = c0 + c1;
        int x = s;
#pragma unroll
        for (int off = 1; off < 64; off <<= 1) {
            int u = __shfl_up(x, off, 64);
            if (lane >= off) x += u;
        }
        if (lane == 63) wsum[wv] = x;
        __syncthreads();
        if (wv == 0 && lane < 16) {
            int w0 = wsum[lane];
            int y = w0;
#pragma unroll
            for (int off = 1; off < 16; off <<= 1) {
                int u = __shfl_up(y, off, 64);
                if (lane >= off) y += u;
            }
            wsum[lane] = y - w0;
        }
        __syncthreads();
        int bse = wsum[wv] + (x - s);
        if (i0 <= nbuk) lb[i0] = bse;
        if (i1 <= nbuk) lb[i1] = bse + c0;
        if (i1 + 1 == nbuk || (i1 == nbuk - 1)) lb[nbuk] = bse + c0 + c1;
        if (i0 == nbuk - 1) lb[nbuk] = bse + c0;   // nbuk even case
    }
    __syncthreads();
    // phase 3: place-cursor = lb
    for (int k = tid; k < nbuk; k += 1024) cur[k] = lb[k];
    __syncthreads();
    // phase 4: place records bucket-sorted into LDS
    for (int i = e0 + tid; i < e1; i += 1024) {
        int r = rows[i], c = cols[i];
        int k = r >> 6;
        int p = atomicAdd(&cur[k], 1);
        recs[p] = (c << 6) | (r & 63);
    }
    __syncthreads();
    // phase 5: reserve global segments (cur[k] = global base)
    for (int k = tid; k < nbuk; k += 1024) {
        int c = lb[k + 1] - lb[k];
        cur[k] = c ? atomicAdd(&gcursor[k], c) : 0;
    }
    __syncthreads();
    // phase 6: flush runs, wave per bucket, coalesced
    for (int k = wv; k < nbuk; k += 16) {
        int s = lb[k], e = lb[k + 1];
        int g = cur[k];
        for (int j = s + lane; j < e; j += 64)
            recbuf[g + (j - s)] = recs[j];
    }
}

// ---------- K3b: per-bucket counting sort ----------
__global__ __launch_bounds__(256) void bucket_sort_kernel(const int* __restrict__ recbuf,
                                                          const int* __restrict__ bOffs,
                                                          int* __restrict__ clist,
                                                          int* __restrict__ offs,
                                                          int n, int nbuk) {
    __shared__ int hist[NPB];
    __shared__ int cur[NPB];
    int b = blockIdx.x, tid = threadIdx.x;
    int base = bOffs[b];
    int cnt = bOffs[b + 1] - base;
    if (tid < NPB) hist[tid] = 0;
    __syncthreads();
    for (int i = tid; i < cnt; i += 256) atomicAdd(&hist[recbuf[base + i] & 63], 1);
    __syncthreads();
    if (tid < 64) {
        int h = hist[tid], v = h;
#pragma unroll
        for (int off = 1; off < 64; off <<= 1) {
            int u = __shfl_up(v, off, 64);
            if (tid >= off) v += u;
        }
        cur[tid] = v - h;
        int g = b * NPB + tid;
        if (g < n) offs[g] = base + v - h;
    }
    if (b == 0 && tid == 0) offs[n] = bOffs[nbuk];
    __syncthreads();
    for (int i = tid; i < cnt; i += 256) {
        int r = recbuf[base + i];
        int p = atomicAdd(&cur[r & 63], 1);
        clist[base + p] = r >> 6;
    }
}

// ---------- K4: gather-aggregate in bf16: h0h = bf16((1+eps)*x + sum_nb x) ----------
// One wave per node. 16 lanes per row (short8 = 16B/lane), 4-way edge interleave.
// Split into two half-grid dispatches (base_node) for profiler visibility.
__global__ __launch_bounds__(256) void agg_kernel(const unsigned short* __restrict__ xh,
                                                  const int* __restrict__ offs,
                                                  const int* __restrict__ clist,
                                                  const float* __restrict__ epsPtr,
                                                  unsigned short* __restrict__ h0h,
                                                  int base_node, int n_end) {
    int wave = threadIdx.x >> 6, lane = threadIdx.x & 63;
    int node = base_node + blockIdx.x * 4 + wave;
    if (node >= n_end) return;
    int qt = lane >> 4;          // which edge within group of 4
    int c16 = lane & 15;         // channel chunk: channels 8*c16 .. 8*c16+7
    const short8* xh8 = (const short8*)xh;   // row r chunk c -> index r*16 + c
    float acc[8];
#pragma unroll
    for (int j = 0; j < 8; j++) acc[j] = 0.f;
    int s = offs[node], e = offs[node + 1];
    int i = s;
    for (; i + 16 <= e; i += 16) {
        int c[4];
#pragma unroll
        for (int u = 0; u < 4; u++) c[u] = clist[i + 4 * u + qt];
        short8 v[4];
#pragma unroll
        for (int u = 0; u < 4; u++) v[u] = xh8[(size_t)c[u] * 16 + c16];
#pragma unroll
        for (int u = 0; u < 4; u++)
#pragma unroll
            for (int j = 0; j < 8; j++) acc[j] += b2f((unsigned short)v[u][j]);
    }
    if (i < e) {
        int c[4];
#pragma unroll
        for (int u = 0; u < 4; u++) {
            int idx = i + 4 * u + qt;
            c[u] = (idx < e) ? clist[idx] : -1;
        }
        short8 v[4];
#pragma unroll
        for (int u = 0; u < 4; u++)
            v[u] = xh8[(size_t)(c[u] < 0 ? 0 : c[u]) * 16 + c16];
#pragma unroll
        for (int u = 0; u < 4; u++) {
            if (c[u] >= 0) {
#pragma unroll
                for (int j = 0; j < 8; j++) acc[j] += b2f((unsigned short)v[u][j]);
            }
        }
    }
    // reduce the 4 quarters: lanes {c16, c16+16, c16+32, c16+48} hold partials
#pragma unroll
    for (int j = 0; j < 8; j++) {
        acc[j] += __shfl_xor(acc[j], 16, 64);
        acc[j] += __shfl_xor(acc[j], 32, 64);
    }
    if (qt == 0) {
        float sc = 1.0f + epsPtr[0];
        short8 xv = xh8[(size_t)node * 16 + c16];
        short8 o;
#pragma unroll
        for (int j = 0; j < 8; j++) {
            float r = fmaf(sc, b2f((unsigned short)xv[j]), acc[j]);
            o[j] = (short)f2b(r);
        }
        ((short8*)h0h)[(size_t)node * 16 + c16] = o;
    }
}

// ---------- K5: MFMA GEMM1: h1 = h0h @ W1^T + b1 (bf16 in, fp32 acc) + BN partials ----------
// Stats epilogue is ATOMIC-FREE: per-block partial sums -> partials[block][256].
#define WLD 136   // padded LDS row stride (elements)
__global__ __launch_bounds__(256, 2) void gemm1_mfma_kernel(const unsigned short* __restrict__ h0h,
                                                            const unsigned short* __restrict__ w1h,
                                                            const float* __restrict__ b1,
                                                            unsigned short* __restrict__ h1h,
                                                            float* __restrict__ partials, int n) {
    __shared__ unsigned short wl[128 * WLD];
    __shared__ float red[4 * 256];
    int tid = threadIdx.x;
    for (int i = tid; i < 128 * 16; i += 256) {
        int r = i >> 4, ch = i & 15;
        *(short8*)(wl + r * WLD + ch * 8) = *(const short8*)(w1h + r * 128 + ch * 8);
    }
    __syncthreads();

    int wv = tid >> 6, lane = tid & 63;
    int q = lane >> 4, c15 = lane & 15;
    int rowbase = blockIdx.x * 64 + wv * 16;
    int arow = rowbase + c15; if (arow >= n) arow = n - 1;
    const unsigned short* aptr = h0h + (size_t)arow * 128 + q * 8;

    float4v acc[8];
#pragma unroll
    for (int nt = 0; nt < 8; nt++) {
        float bb = b1[nt * 16 + c15];
        acc[nt] = (float4v){bb, bb, bb, bb};
    }
#pragma unroll
    for (int ks = 0; ks < 4; ks++) {
        short8 a = *(const short8*)(aptr + ks * 32);
        const unsigned short* wp = wl + q * 8 + ks * 32;
#pragma unroll
        for (int nt = 0; nt < 8; nt++) {
            short8 b = *(const short8*)(wp + (nt * 16 + c15) * WLD);
            acc[nt] = __builtin_amdgcn_mfma_f32_16x16x32_bf16(a, b, acc[nt], 0, 0, 0);
        }
    }

    // epilogue: store h1h (bf16) + per-col partial sums (no global atomics)
    float sum[8], sq[8];
#pragma unroll
    for (int nt = 0; nt < 8; nt++) {
        sum[nt] = 0.f; sq[nt] = 0.f;
#pragma unroll
        for (int r = 0; r < 4; r++) {
            int row = rowbase + q * 4 + r;
            if (row < n) {
                float v = acc[nt][r];
                h1h[(size_t)row * 128 + nt * 16 + c15] = f2b(v);
                sum[nt] += v; sq[nt] += v * v;
            }
        }
        sum[nt] += __shfl_xor(sum[nt], 16, 64);
        sum[nt] += __shfl_xor(sum[nt], 32, 64);
        sq[nt]  += __shfl_xor(sq[nt], 16, 64);
        sq[nt]  += __shfl_xor(sq[nt], 32, 64);
    }
    if (lane < 16) {
#pragma unroll
        for (int nt = 0; nt < 8; nt++) {
            red[wv * 256 + nt * 16 + c15] = sum[nt];
            red[wv * 256 + 128 + nt * 16 + c15] = sq[nt];
        }
    }
    __syncthreads();
    if (wv == 0) {
        float* pout = partials + (size_t)blockIdx.x * 256;
        for (int c = lane; c < 128; c += 64) {
            float S = red[c] + red[256 + c] + red[512 + c] + red[768 + c];
            float Q = red[128 + c] + red[384 + c] + red[640 + c] + red[896 + c];
            pout[c] = S;
            pout[128 + c] = Q;
        }
    }
}

// ---------- K6: reduce per-block partials -> stats (16-deep atomic chains only) ----------
__global__ __launch_bounds__(256) void bn_reduce_kernel(const float* __restrict__ partials,
                                                        float* __restrict__ stats, int nb) {
    int t = threadIdx.x;
    int per = (nb + gridDim.x - 1) / gridDim.x;
    int j0 = blockIdx.x * per, j1 = min(nb, j0 + per);
    float s = 0.f;
    for (int j = j0; j < j1; j++) s += partials[(size_t)j * 256 + t];
    atomicAdd(&stats[t], s);
}

// ---------- K7: MFMA GEMM2: out = relu(BN(h1h)) @ W2^T + b2, fp32 out ----------
// BN finalize fused into prologue: each block derives scale/shift from stats.
__global__ __launch_bounds__(256, 2) void gemm2_mfma_kernel(const unsigned short* __restrict__ h1h,
                                                            const unsigned short* __restrict__ w2h,
                                                            const float* __restrict__ b2,
                                                            const float* __restrict__ stats,
                                                            const float* __restrict__ gamma,
                                                            const float* __restrict__ beta,
                                                            float* __restrict__ out, int n) {
    __shared__ unsigned short wl[128 * WLD];
    __shared__ float ssl[256];
    int tid = threadIdx.x;
    for (int i = tid; i < 128 * 16; i += 256) {
        int r = i >> 4, ch = i & 15;
        *(short8*)(wl + r * WLD + ch * 8) = *(const short8*)(w2h + r * 128 + ch * 8);
    }
    if (tid < 128) {
        float inv_n = 1.0f / (float)n;
        float mu = stats[tid] * inv_n;
        float var = stats[F + tid] * inv_n - mu * mu;
        var = fmaxf(var, 0.0f);
        float rs = rsqrtf(var + 1e-5f);
        float s = gamma[tid] * rs;
        ssl[tid] = s;
        ssl[F + tid] = beta[tid] - mu * s;
    }
    __syncthreads();

    int wv = tid >> 6, lane = tid & 63;
    int q = lane >> 4, c15 = lane & 15;
    int rowbase = blockIdx.x * 64 + wv * 16;
    int arow = rowbase + c15; if (arow >= n) arow = n - 1;
    const unsigned short* aptr = h1h + (size_t)arow * 128 + q * 8;

    float4v acc[8];
#pragma unroll
    for (int nt = 0; nt < 8; nt++) {
        float bb = b2[nt * 16 + c15];
        acc[nt] = (float4v){bb, bb, bb, bb};
    }
#pragma unroll
    for (int ks = 0; ks < 4; ks++) {
        short8 araw = *(const short8*)(aptr + ks * 32);
        const float* ssp = ssl + ks * 32 + q * 8;
        float4 s0 = *(const float4*)(ssp);
        float4 s1 = *(const float4*)(ssp + 4);
        float4 t0 = *(const float4*)(ssp + 128);
        float4 t1 = *(const float4*)(ssp + 132);
        short8 a;
        a[0] = (short)f2b(fmaxf(fmaf(b2f((unsigned short)araw[0]), s0.x, t0.x), 0.f));
        a[1] = (short)f2b(fmaxf(fmaf(b2f((unsigned short)araw[1]), s0.y, t0.y), 0.f));
        a[2] = (short)f2b(fmaxf(fmaf(b2f((unsigned short)araw[2]), s0.z, t0.z), 0.f));
        a[3] = (short)f2b(fmaxf(fmaf(b2f((unsigned short)araw[3]), s0.w, t0.w), 0.f));
        a[4] = (short)f2b(fmaxf(fmaf(b2f((unsigned short)araw[4]), s1.x, t1.x), 0.f));
        a[5] = (short)f2b(fmaxf(fmaf(b2f((unsigned short)araw[5]), s1.y, t1.y), 0.f));
        a[6] = (short)f2b(fmaxf(fmaf(b2f((unsigned short)araw[6]), s1.z, t1.z), 0.f));
        a[7] = (short)f2b(fmaxf(fmaf(b2f((unsigned short)araw[7]), s1.w, t1.w), 0.f));
        const unsigned short* wp = wl + q * 8 + ks * 32;
#pragma unroll
        for (int nt = 0; nt < 8; nt++) {
            short8 b = *(const short8*)(wp + (nt * 16 + c15) * WLD);
            acc[nt] = __builtin_amdgcn_mfma_f32_16x16x32_bf16(a, b, acc[nt], 0, 0, 0);
        }
    }
#pragma unroll
    for (int nt = 0; nt < 8; nt++) {
#pragma unroll
        for (int r = 0; r < 4; r++) {
            int row = rowbase + q * 4 + r;
            if (row < n)
                out[(size_t)row * 128 + nt * 16 + c15] = acc[nt][r];
        }
    }
}

extern "C" void kernel_launch(void* const* d_in, const int* in_sizes, int n_in,
                              void* d_out, int out_size, void* d_ws, size_t ws_size,
                              hipStream_t stream) {
    const float* x     = (const float*)d_in[0];
    const int*   ei    = (const int*)d_in[1];
    const float* eps   = (const float*)d_in[2];
    const float* W1    = (const float*)d_in[3];
    const float* b1    = (const float*)d_in[4];
    const float* gamma = (const float*)d_in[5];
    const float* beta  = (const float*)d_in[6];
    const float* W2    = (const float*)d_in[7];
    const float* b2    = (const float*)d_in[8];
    float* out = (float*)d_out;

    const int E = in_sizes[1] / 2;
    const int n = in_sizes[0] / F;
    const int nbuk = (n + NPB - 1) / NPB;   // 1563
    const int ntiles = (n + 63) / 64;       // 1563
    // scatter blocks: chunk must fit RECCAP
    int SB = (E + RECCAP - 1) / RECCAP;
    if (SB < 128) SB = 128;

    char* w = (char*)d_ws;
    auto alloc = [&](size_t bytes) -> void* {
        void* p = (void*)w;
        w += (bytes + 255) & ~(size_t)255;
        return p;
    };
    int*            bucketCnt = (int*)alloc((size_t)nbuk * 4);
    int*            bOffs     = (int*)alloc((size_t)(nbuk + 1) * 4);
    int*            gcursor   = (int*)alloc((size_t)nbuk * 4);
    int*            offs      = (int*)alloc((size_t)(n + 1) * 4);
    float*          stats     = (float*)alloc(256 * 4);
    float*          partials  = (float*)alloc((size_t)ntiles * 256 * 4);
    unsigned short* w1h       = (unsigned short*)alloc(F * F * 2);
    unsigned short* w2h       = (unsigned short*)alloc(F * F * 2);
    int*            recbuf    = (int*)alloc((size_t)E * 4);
    int*            clist     = (int*)alloc((size_t)E * 4);
    unsigned short* xh        = (unsigned short*)alloc((size_t)n * F * 2);
    unsigned short* h0h       = (unsigned short*)alloc((size_t)n * F * 2);
    unsigned short* h1h       = (unsigned short*)alloc((size_t)n * F * 2);

    const int* rows = ei;
    const int* cols = ei + E;

    conv_kernel<<<(n * F / 8 + 255) / 256, 256, 0, stream>>>(x, xh, n * F, W1, W2, w1h, w2h,
                                                             bucketCnt, nbuk, stats);
    bucket_hist_kernel<<<256, 256, nbuk * 4, stream>>>(rows, bucketCnt, E, nbuk);
    scan_buckets_kernel<<<1, 256, 0, stream>>>(bucketCnt, bOffs, gcursor, nbuk);
    binned_scatter_kernel<<<SB, 1024, 0, stream>>>(rows, cols, gcursor, recbuf, E, nbuk);
    bucket_sort_kernel<<<nbuk, 256, 0, stream>>>(recbuf, bOffs, clist, offs, n, nbuk);

    int nhalf = n / 2;
    agg_kernel<<<(nhalf + 3) / 4, 256, 0, stream>>>(xh, offs, clist, eps, h0h, 0, nhalf);
    agg_kernel<<<(n - nhalf + 3) / 4, 256, 0, stream>>>(xh, offs, clist, eps, h0h, nhalf, n);

    gemm1_mfma_kernel<<<ntiles, 256, 0, stream>>>(h0h, w1h, b1, h1h, partials, n);
    bn_reduce_kernel<<<16, 256, 0, stream>>>(partials, stats, ntiles);
    gemm2_mfma_kernel<<<ntiles, 256, 0, stream>>>(h1h, w2h, b2, stats, gamma, beta, out, n);
}

// Round 12
// 287.503 us; speedup vs baseline: 1.3369x; 1.0206x over previous
//
#include <hip/hip_runtime.h>

// GIN layer: agg = segment_sum(x[col], row); h = (1+eps)*x + agg;
// h = h@W1.T + b1; BN(train); ReLU; out = h@W2.T + b2
// N=100000, E=1600000, F=128. Inputs fp32; internal bf16 + MFMA.

#define F 128
#define NPB 64          // nodes per bucket
#define NBUKMAX 1600    // static LDS bound for buckets
#define RECCAP 6272     // staged recs per scatter block (>= ceil(E/SB))

typedef __attribute__((ext_vector_type(8))) short short8;
typedef __attribute__((ext_vector_type(4))) float float4v;

__device__ inline float b2f(unsigned short u) {
    union { unsigned int i; float f; } v; v.i = ((unsigned int)u) << 16; return v.f;
}
__device__ inline unsigned short f2b(float f) {
    union { float f; unsigned int i; } v; v.f = f;
    unsigned int r = v.i + 0x7FFFu + ((v.i >> 16) & 1u);
    return (unsigned short)(r >> 16);
}

// ---------- K0: convert x -> bf16, W1,W2 -> bf16, zero bucketCnt+stats (fused) ----------
__global__ __launch_bounds__(256) void conv_kernel(const float* __restrict__ x,
                                                   unsigned short* __restrict__ xh, int total,
                                                   const float* __restrict__ W1,
                                                   const float* __restrict__ W2,
                                                   unsigned short* __restrict__ w1h,
                                                   unsigned short* __restrict__ w2h,
                                                   int* __restrict__ bucketCnt, int nbuk,
                                                   float* __restrict__ stats) {
    int t = blockIdx.x * 256 + threadIdx.x;
    int i = t * 8;
    if (i < total) {
        float4 v0 = *(const float4*)(x + i);
        float4 v1 = *(const float4*)(x + i + 4);
        short8 o;
        o[0] = (short)f2b(v0.x); o[1] = (short)f2b(v0.y); o[2] = (short)f2b(v0.z); o[3] = (short)f2b(v0.w);
        o[4] = (short)f2b(v1.x); o[5] = (short)f2b(v1.y); o[6] = (short)f2b(v1.z); o[7] = (short)f2b(v1.w);
        *(short8*)(xh + i) = o;
    }
    if (t < F * F) {
        w1h[t] = f2b(W1[t]);
        w2h[t] = f2b(W2[t]);
    }
    if (blockIdx.x == 0) {
        for (int k = threadIdx.x; k < nbuk; k += 256) bucketCnt[k] = 0;
    } else if (blockIdx.x == 1) {
        if (threadIdx.x < 256) stats[threadIdx.x] = 0.f;
    }
}

// ---------- K1: bucket histogram (LDS-aggregated) ----------
__global__ __launch_bounds__(256) void bucket_hist_kernel(const int* __restrict__ rows,
                                                          int* __restrict__ bucketCnt,
                                                          int E, int nbuk) {
    extern __shared__ int bh[];
    int tid = threadIdx.x;
    for (int i = tid; i < nbuk; i += 256) bh[i] = 0;
    __syncthreads();
    int stride = gridDim.x * 256;
    for (int i = blockIdx.x * 256 + tid; i < E; i += stride)
        atomicAdd(&bh[rows[i] >> 6], 1);
    __syncthreads();
    for (int b = tid; b < nbuk; b += 256) {
        int c = bh[b];
        if (c) atomicAdd(&bucketCnt[b], c);
    }
}

// ---------- K2: exclusive scan of bucket counts ----------
__global__ void scan_buckets_kernel(const int* __restrict__ bucketCnt, int* __restrict__ bOffs,
                                    int* __restrict__ gcursor, int nbuk) {
    const int SEG = 7;
    __shared__ int tmp[256];
    int t = threadIdx.x;
    int base = t * SEG;
    int v[SEG], s = 0;
#pragma unroll
    for (int j = 0; j < SEG; j++) {
        int idx = base + j;
        v[j] = (idx < nbuk) ? bucketCnt[idx] : 0;
        s += v[j];
    }
    tmp[t] = s;
    __syncthreads();
    for (int off = 1; off < 256; off <<= 1) {
        int u = (t >= off) ? tmp[t - off] : 0;
        __syncthreads();
        tmp[t] += u;
        __syncthreads();
    }
    int run = tmp[t] - s;
#pragma unroll
    for (int j = 0; j < SEG; j++) {
        int idx = base + j;
        if (idx < nbuk) { bOffs[idx] = run; gcursor[idx] = run; }
        run += v[j];
    }
    if (t == 255) bOffs[nbuk] = tmp[255];
}

// ---------- K3: LDS-staged binned scatter ----------
// Block sorts its edge chunk by bucket in LDS, reserves one contiguous global
// segment per bucket, then flushes each bucket's run with coalesced writes.
__global__ __launch_bounds__(1024) void binned_scatter_kernel(const int* __restrict__ rows,
                                                              const int* __restrict__ cols,
                                                              int* __restrict__ gcursor,
                                                              int* __restrict__ recbuf,
                                                              int E, int nbuk) {
    __shared__ int cur[NBUKMAX];        // hist -> place-cursor -> global base
    __shared__ int lb[NBUKMAX + 1];     // exclusive prefix (local)
    __shared__ int recs[RECCAP];        // staged records, bucket-sorted
    __shared__ int wsum[17];
    int tid = threadIdx.x;
    int lane = tid & 63, wv = tid >> 6;
    int chunk = (E + gridDim.x - 1) / gridDim.x;
    int e0 = blockIdx.x * chunk;
    int e1 = min(E, e0 + chunk);
    // phase 1: hist into cur
    for (int k = tid; k < nbuk; k += 1024) cur[k] = 0;
    __syncthreads();
    for (int i = e0 + tid; i < e1; i += 1024)
        atomicAdd(&cur[rows[i] >> 6], 1);
    __syncthreads();
    // phase 2: exclusive scan cur -> lb (2 entries/thread, register wave scan)
    {
        int i0 = 2 * tid, i1 = 2 * tid + 1;
        int c0 = (i0 < nbuk) ? cur[i0] : 0;
        int c1 = (i1 < nbuk) ? cur[i1] : 0;
        int s = c0 + c1;
        int x = s;
#pragma unroll
        for (int off = 1; off < 64; off <<= 1) {
            int u = __shfl_up(x, off, 64);
            if (lane >= off) x += u;
        }
        if (lane == 63) wsum[wv] = x;
        __syncthreads();
        if (wv == 0 && lane < 16) {
            int w0 = wsum[lane];
            int y = w0;
#pragma unroll
            for (int off = 1; off < 16; off <<= 1) {
                int u = __shfl_up(y, off, 64);
                if (lane >= off) y += u;
            }
            wsum[lane] = y - w0;
        }
        __syncthreads();
        int bse = wsum[wv] + (x - s);
        if (i0 <= nbuk) lb[i0] = bse;
        if (i1 <= nbuk) lb[i1] = bse + c0;
        if (i1 + 1 == nbuk || (i1 == nbuk - 1)) lb[nbuk] = bse + c0 + c1;
        if (i0 == nbuk - 1) lb[nbuk] = bse + c0;   // nbuk even case
    }
    __syncthreads();
    // phase 3: place-cursor = lb
    for (int k = tid; k < nbuk; k += 1024) cur[k] = lb[k];
    __syncthreads();
    // phase 4: place records bucket-sorted into LDS
    for (int i = e0 + tid; i < e1; i += 1024) {
        int r = rows[i], c = cols[i];
        int k = r >> 6;
        int p = atomicAdd(&cur[k], 1);
        recs[p] = (c << 6) | (r & 63);
    }
    __syncthreads();
    // phase 5: reserve global segments (cur[k] = global base)
    for (int k = tid; k < nbuk; k += 1024) {
        int c = lb[k + 1] - lb[k];
        cur[k] = c ? atomicAdd(&gcursor[k], c) : 0;
    }
    __syncthreads();
    // phase 6: flush runs, wave per bucket, coalesced
    for (int k = wv; k < nbuk; k += 16) {
        int s = lb[k], e = lb[k + 1];
        int g = cur[k];
        for (int j = s + lane; j < e; j += 64)
            recbuf[g + (j - s)] = recs[j];
    }
}

// ---------- K3b: per-bucket counting sort ----------
__global__ __launch_bounds__(256) void bucket_sort_kernel(const int* __restrict__ recbuf,
                                                          const int* __restrict__ bOffs,
                                                          int* __restrict__ clist,
                                                          int* __restrict__ offs,
                                                          int n, int nbuk) {
    __shared__ int hist[NPB];
    __shared__ int cur[NPB];
    int b = blockIdx.x, tid = threadIdx.x;
    int base = bOffs[b];
    int cnt = bOffs[b + 1] - base;
    if (tid < NPB) hist[tid] = 0;
    __syncthreads();
    for (int i = tid; i < cnt; i += 256) atomicAdd(&hist[recbuf[base + i] & 63], 1);
    __syncthreads();
    if (tid < 64) {
        int h = hist[tid], v = h;
#pragma unroll
        for (int off = 1; off < 64; off <<= 1) {
            int u = __shfl_up(v, off, 64);
            if (tid >= off) v += u;
        }
        cur[tid] = v - h;
        int g = b * NPB + tid;
        if (g < n) offs[g] = base + v - h;
    }
    if (b == 0 && tid == 0) offs[n] = bOffs[nbuk];
    __syncthreads();
    for (int i = tid; i < cnt; i += 256) {
        int r = recbuf[base + i];
        int p = atomicAdd(&cur[r & 63], 1);
        clist[base + p] = r >> 6;
    }
}

// ---------- K4: gather-aggregate in bf16: h0h = bf16((1+eps)*x + sum_nb x) ----------
// One wave per node. 16 lanes per row (short8 = 16B/lane), 4-way edge interleave.
__global__ __launch_bounds__(256) void agg_kernel(const unsigned short* __restrict__ xh,
                                                  const int* __restrict__ offs,
                                                  const int* __restrict__ clist,
                                                  const float* __restrict__ epsPtr,
                                                  unsigned short* __restrict__ h0h, int n) {
    int wave = threadIdx.x >> 6, lane = threadIdx.x & 63;
    int node = blockIdx.x * 4 + wave;
    if (node >= n) return;
    int qt = lane >> 4;          // which edge within group of 4
    int c16 = lane & 15;         // channel chunk: channels 8*c16 .. 8*c16+7
    const short8* xh8 = (const short8*)xh;   // row r chunk c -> index r*16 + c
    float acc[8];
#pragma unroll
    for (int j = 0; j < 8; j++) acc[j] = 0.f;
    int s = offs[node], e = offs[node + 1];
    int i = s;
    for (; i + 16 <= e; i += 16) {
        int c[4];
#pragma unroll
        for (int u = 0; u < 4; u++) c[u] = clist[i + 4 * u + qt];
        short8 v[4];
#pragma unroll
        for (int u = 0; u < 4; u++) v[u] = xh8[(size_t)c[u] * 16 + c16];
#pragma unroll
        for (int u = 0; u < 4; u++)
#pragma unroll
            for (int j = 0; j < 8; j++) acc[j] += b2f((unsigned short)v[u][j]);
    }
    if (i < e) {
        int c[4];
#pragma unroll
        for (int u = 0; u < 4; u++) {
            int idx = i + 4 * u + qt;
            c[u] = (idx < e) ? clist[idx] : -1;
        }
        short8 v[4];
#pragma unroll
        for (int u = 0; u < 4; u++)
            v[u] = xh8[(size_t)(c[u] < 0 ? 0 : c[u]) * 16 + c16];
#pragma unroll
        for (int u = 0; u < 4; u++) {
            if (c[u] >= 0) {
#pragma unroll
                for (int j = 0; j < 8; j++) acc[j] += b2f((unsigned short)v[u][j]);
            }
        }
    }
    // reduce the 4 quarters: lanes {c16, c16+16, c16+32, c16+48} hold partials
#pragma unroll
    for (int j = 0; j < 8; j++) {
        acc[j] += __shfl_xor(acc[j], 16, 64);
        acc[j] += __shfl_xor(acc[j], 32, 64);
    }
    if (qt == 0) {
        float sc = 1.0f + epsPtr[0];
        short8 xv = xh8[(size_t)node * 16 + c16];
        short8 o;
#pragma unroll
        for (int j = 0; j < 8; j++) {
            float r = fmaf(sc, b2f((unsigned short)xv[j]), acc[j]);
            o[j] = (short)f2b(r);
        }
        ((short8*)h0h)[(size_t)node * 16 + c16] = o;
    }
}

// ---------- K5: MFMA GEMM1: h1 = h0h @ W1^T + b1 (bf16 in, fp32 acc) + BN partials ----------
// Stats epilogue is ATOMIC-FREE: per-block partial sums -> partials[block][256].
#define WLD 136   // padded LDS row stride (elements)
__global__ __launch_bounds__(256, 2) void gemm1_mfma_kernel(const unsigned short* __restrict__ h0h,
                                                            const unsigned short* __restrict__ w1h,
                                                            const float* __restrict__ b1,
                                                            unsigned short* __restrict__ h1h,
                                                            float* __restrict__ partials, int n) {
    __shared__ unsigned short wl[128 * WLD];
    __shared__ float red[4 * 256];
    int tid = threadIdx.x;
    for (int i = tid; i < 128 * 16; i += 256) {
        int r = i >> 4, ch = i & 15;
        *(short8*)(wl + r * WLD + ch * 8) = *(const short8*)(w1h + r * 128 + ch * 8);
    }
    __syncthreads();

    int wv = tid >> 6, lane = tid & 63;
    int q = lane >> 4, c15 = lane & 15;
    int rowbase = blockIdx.x * 64 + wv * 16;
    int arow = rowbase + c15; if (arow >= n) arow = n - 1;
    const unsigned short* aptr = h0h + (size_t)arow * 128 + q * 8;

    float4v acc[8];
#pragma unroll
    for (int nt = 0; nt < 8; nt++) {
        float bb = b1[nt * 16 + c15];
        acc[nt] = (float4v){bb, bb, bb, bb};
    }
#pragma unroll
    for (int ks = 0; ks < 4; ks++) {
        short8 a = *(const short8*)(aptr + ks * 32);
        const unsigned short* wp = wl + q * 8 + ks * 32;
#pragma unroll
        for (int nt = 0; nt < 8; nt++) {
            short8 b = *(const short8*)(wp + (nt * 16 + c15) * WLD);
            acc[nt] = __builtin_amdgcn_mfma_f32_16x16x32_bf16(a, b, acc[nt], 0, 0, 0);
        }
    }

    // epilogue: store h1h (bf16) + per-col partial sums (no global atomics)
    float sum[8], sq[8];
#pragma unroll
    for (int nt = 0; nt < 8; nt++) {
        sum[nt] = 0.f; sq[nt] = 0.f;
#pragma unroll
        for (int r = 0; r < 4; r++) {
            int row = rowbase + q * 4 + r;
            if (row < n) {
                float v = acc[nt][r];
                h1h[(size_t)row * 128 + nt * 16 + c15] = f2b(v);
                sum[nt] += v; sq[nt] += v * v;
            }
        }
        sum[nt] += __shfl_xor(sum[nt], 16, 64);
        sum[nt] += __shfl_xor(sum[nt], 32, 64);
        sq[nt]  += __shfl_xor(sq[nt], 16, 64);
        sq[nt]  += __shfl_xor(sq[nt], 32, 64);
    }
    if (lane < 16) {
#pragma unroll
        for (int nt = 0; nt < 8; nt++) {
            red[wv * 256 + nt * 16 + c15] = sum[nt];
            red[wv * 256 + 128 + nt * 16 + c15] = sq[nt];
        }
    }
    __syncthreads();
    if (wv == 0) {
        float* pout = partials + (size_t)blockIdx.x * 256;
        for (int c = lane; c < 128; c += 64) {
            float S = red[c] + red[256 + c] + red[512 + c] + red[768 + c];
            float Q = red[128 + c] + red[384 + c] + red[640 + c] + red[896 + c];
            pout[c] = S;
            pout[128 + c] = Q;
        }
    }
}

// ---------- K6: reduce per-block partials -> stats (16-deep atomic chains only) ----------
__global__ __launch_bounds__(256) void bn_reduce_kernel(const float* __restrict__ partials,
                                                        float* __restrict__ stats, int nb) {
    int t = threadIdx.x;
    int per = (nb + gridDim.x - 1) / gridDim.x;
    int j0 = blockIdx.x * per, j1 = min(nb, j0 + per);
    float s = 0.f;
    for (int j = j0; j < j1; j++) s += partials[(size_t)j * 256 + t];
    atomicAdd(&stats[t], s);
}

// ---------- K7: MFMA GEMM2: out = relu(BN(h1h)) @ W2^T + b2, fp32 out ----------
// BN finalize fused into prologue: each block derives scale/shift from stats.
__global__ __launch_bounds__(256, 2) void gemm2_mfma_kernel(const unsigned short* __restrict__ h1h,
                                                            const unsigned short* __restrict__ w2h,
                                                            const float* __restrict__ b2,
                                                            const float* __restrict__ stats,
                                                            const float* __restrict__ gamma,
                                                            const float* __restrict__ beta,
                                                            float* __restrict__ out, int n) {
    __shared__ unsigned short wl[128 * WLD];
    __shared__ float ssl[256];
    int tid = threadIdx.x;
    for (int i = tid; i < 128 * 16; i += 256) {
        int r = i >> 4, ch = i & 15;
        *(short8*)(wl + r * WLD + ch * 8) = *(const short8*)(w2h + r * 128 + ch * 8);
    }
    if (tid < 128) {
        float inv_n = 1.0f / (float)n;
        float mu = stats[tid] * inv_n;
        float var = stats[F + tid] * inv_n - mu * mu;
        var = fmaxf(var, 0.0f);
        float rs = rsqrtf(var + 1e-5f);
        float s = gamma[tid] * rs;
        ssl[tid] = s;
        ssl[F + tid] = beta[tid] - mu * s;
    }
    __syncthreads();

    int wv = tid >> 6, lane = tid & 63;
    int q = lane >> 4, c15 = lane & 15;
    int rowbase = blockIdx.x * 64 + wv * 16;
    int arow = rowbase + c15; if (arow >= n) arow = n - 1;
    const unsigned short* aptr = h1h + (size_t)arow * 128 + q * 8;

    float4v acc[8];
#pragma unroll
    for (int nt = 0; nt < 8; nt++) {
        float bb = b2[nt * 16 + c15];
        acc[nt] = (float4v){bb, bb, bb, bb};
    }
#pragma unroll
    for (int ks = 0; ks < 4; ks++) {
        short8 araw = *(const short8*)(aptr + ks * 32);
        const float* ssp = ssl + ks * 32 + q * 8;
        float4 s0 = *(const float4*)(ssp);
        float4 s1 = *(const float4*)(ssp + 4);
        float4 t0 = *(const float4*)(ssp + 128);
        float4 t1 = *(const float4*)(ssp + 132);
        short8 a;
        a[0] = (short)f2b(fmaxf(fmaf(b2f((unsigned short)araw[0]), s0.x, t0.x), 0.f));
        a[1] = (short)f2b(fmaxf(fmaf(b2f((unsigned short)araw[1]), s0.y, t0.y), 0.f));
        a[2] = (short)f2b(fmaxf(fmaf(b2f((unsigned short)araw[2]), s0.z, t0.z), 0.f));
        a[3] = (short)f2b(fmaxf(fmaf(b2f((unsigned short)araw[3]), s0.w, t0.w), 0.f));
        a[4] = (short)f2b(fmaxf(fmaf(b2f((unsigned short)araw[4]), s1.x, t1.x), 0.f));
        a[5] = (short)f2b(fmaxf(fmaf(b2f((unsigned short)araw[5]), s1.y, t1.y), 0.f));
        a[6] = (short)f2b(fmaxf(fmaf(b2f((unsigned short)araw[6]), s1.z, t1.z), 0.f));
        a[7] = (short)f2b(fmaxf(fmaf(b2f((unsigned short)araw[7]), s1.w, t1.w), 0.f));
        const unsigned short* wp = wl + q * 8 + ks * 32;
#pragma unroll
        for (int nt = 0; nt < 8; nt++) {
            short8 b = *(const short8*)(wp + (nt * 16 + c15) * WLD);
            acc[nt] = __builtin_amdgcn_mfma_f32_16x16x32_bf16(a, b, acc[nt], 0, 0, 0);
        }
    }
#pragma unroll
    for (int nt = 0; nt < 8; nt++) {
#pragma unroll
        for (int r = 0; r < 4; r++) {
            int row = rowbase + q * 4 + r;
            if (row < n)
                out[(size_t)row * 128 + nt * 16 + c15] = acc[nt][r];
        }
    }
}

extern "C" void kernel_launch(void* const* d_in, const int* in_sizes, int n_in,
                              void* d_out, int out_size, void* d_ws, size_t ws_size,
                              hipStream_t stream) {
    const float* x     = (const float*)d_in[0];
    const int*   ei    = (const int*)d_in[1];
    const float* eps   = (const float*)d_in[2];
    const float* W1    = (const float*)d_in[3];
    const float* b1    = (const float*)d_in[4];
    const float* gamma = (const float*)d_in[5];
    const float* beta  = (const float*)d_in[6];
    const float* W2    = (const float*)d_in[7];
    const float* b2    = (const float*)d_in[8];
    float* out = (float*)d_out;

    const int E = in_sizes[1] / 2;
    const int n = in_sizes[0] / F;
    const int nbuk = (n + NPB - 1) / NPB;   // 1563
    const int ntiles = (n + 63) / 64;       // 1563
    // scatter blocks: chunk must fit RECCAP
    int SB = (E + RECCAP - 1) / RECCAP;     // 256 for E=1.6M
    if (SB < 128) SB = 128;

    char* w = (char*)d_ws;
    auto alloc = [&](size_t bytes) -> void* {
        void* p = (void*)w;
        w += (bytes + 255) & ~(size_t)255;
        return p;
    };
    int*            bucketCnt = (int*)alloc((size_t)nbuk * 4);
    int*            bOffs     = (int*)alloc((size_t)(nbuk + 1) * 4);
    int*            gcursor   = (int*)alloc((size_t)nbuk * 4);
    int*            offs      = (int*)alloc((size_t)(n + 1) * 4);
    float*          stats     = (float*)alloc(256 * 4);
    float*          partials  = (float*)alloc((size_t)ntiles * 256 * 4);
    unsigned short* w1h       = (unsigned short*)alloc(F * F * 2);
    unsigned short* w2h       = (unsigned short*)alloc(F * F * 2);
    int*            recbuf    = (int*)alloc((size_t)E * 4);
    int*            clist     = (int*)alloc((size_t)E * 4);
    unsigned short* xh        = (unsigned short*)alloc((size_t)n * F * 2);
    unsigned short* h0h       = (unsigned short*)alloc((size_t)n * F * 2);
    unsigned short* h1h       = (unsigned short*)alloc((size_t)n * F * 2);

    const int* rows = ei;
    const int* cols = ei + E;

    conv_kernel<<<(n * F / 8 + 255) / 256, 256, 0, stream>>>(x, xh, n * F, W1, W2, w1h, w2h,
                                                             bucketCnt, nbuk, stats);
    bucket_hist_kernel<<<256, 256, nbuk * 4, stream>>>(rows, bucketCnt, E, nbuk);
    scan_buckets_kernel<<<1, 256, 0, stream>>>(bucketCnt, bOffs, gcursor, nbuk);
    binned_scatter_kernel<<<SB, 1024, 0, stream>>>(rows, cols, gcursor, recbuf, E, nbuk);
    bucket_sort_kernel<<<nbuk, 256, 0, stream>>>(recbuf, bOffs, clist, offs, n, nbuk);
    agg_kernel<<<(n + 3) / 4, 256, 0, stream>>>(xh, offs, clist, eps, h0h, n);

    gemm1_mfma_kernel<<<ntiles, 256, 0, stream>>>(h0h, w1h, b1, h1h, partials, n);
    bn_reduce_kernel<<<16, 256, 0, stream>>>(partials, stats, ntiles);
    gemm2_mfma_kernel<<<ntiles, 256, 0, stream>>>(h1h, w2h, b2, stats, gamma, beta, out, n);
}